// Round 7
// baseline (54177.472 us; speedup 1.0000x reference)
//
#include <hip/hip_runtime.h>
#include <math.h>
#include <stdint.h>

#define Bn 256
#define Tn 256
#define Dn 512
#define UNITSn 1024
#define NCn 512
#define G4n 4096
#define KTn 1536   // 512 (x) + 1024 (h)
#define NT 48      // K tiles of 32

typedef unsigned long long u64;
typedef __attribute__((ext_vector_type(4))) double d4;

__device__ __forceinline__ double hsigd(double z) {
    return fmin(fmax(0.2 * z + 0.5, 0.0), 1.0);
}

// pack logit+col into u64: fixed-point (logit+2048)*2^40 (<<10) | (1023-col)
__device__ __forceinline__ u64 packlc(double v, int col) {
    double s = (v + 2048.0) * 1099511627776.0;   // 2^40
    u64 q = (u64)s;                              // < 2^53
    return (q << 10) | (u64)(1023 - col);
}

// In-loop barrier WITHOUT vmcnt drain (r4+, keeps prefetch loads in flight).
#define BARLDS() asm volatile("s_waitcnt lgkmcnt(0)\n\ts_barrier" ::: "memory")

// one-time boot barrier: per-block release+acquire (cost paid once)
__device__ __forceinline__ void gboot(u64* b) {
    __syncthreads();
    if (threadIdx.x == 0) {
        __hip_atomic_fetch_add(b, 1ull, __ATOMIC_RELEASE, __HIP_MEMORY_SCOPE_AGENT);
        int n = 0;
        while (__hip_atomic_load(b, __ATOMIC_RELAXED, __HIP_MEMORY_SCOPE_AGENT) < 512ull) {
            __builtin_amdgcn_s_sleep(2);
            if (++n > 50000) break;  // failsafe: corrupt, never hang
        }
        (void)__hip_atomic_load(b, __ATOMIC_ACQUIRE, __HIP_MEMORY_SCOPE_AGENT);
    }
    __syncthreads();
}

// ---------------- persistent kernel ----------------
// Grid 512 x 256 thr, 2 blocks/CU co-resident (verified r1-r6).
// sync layout (u64 units, stride-16 padded): root1@0, root2@16, boot@32,
// xcnt@48(+8*16), leafx@176(+8*16), leaves2@304(+64*16)
#define AS_STR 33
#define BS_STR 33
#define AS_TILE (64 * AS_STR)    // 2112
#define BS_TILE (32 * BS_STR)    // 1056

__global__ __launch_bounds__(256, 2) void lstm_persistent(
    const float* __restrict__ x,
    const float* __restrict__ W, const float* __restrict__ U,
    const float* __restrict__ bias,
    const float* __restrict__ Wout, const float* __restrict__ bout,
    double* __restrict__ h0buf, double* __restrict__ h1buf,
    u64* __restrict__ slots0, u64* __restrict__ slots1,
    u64* __restrict__ sync, int* __restrict__ out)
{
    __shared__ __align__(16) double smem[2 * AS_TILE + 2 * BS_TILE];

    u64* root1   = sync + 0;
    u64* root2   = sync + 16;
    u64* boot    = sync + 32;
    u64* xcnt    = sync + 48;
    u64* leafx   = sync + 176;
    u64* leaves2 = sync + 304;

    const int tid = threadIdx.x;
    const int bid = blockIdx.x;
    const int leaf = bid >> 3;

    // ---- actual XCD id (robust to dispatch mapping) + one-time census ----
    int xcc;
    asm volatile("s_getreg_b32 %0, hwreg(HW_REG_XCC_ID)" : "=s"(xcc));
    if (tid == 0)
        __hip_atomic_fetch_add(&xcnt[xcc * 16], 1ull, __ATOMIC_RELAXED, __HIP_MEMORY_SCOPE_AGENT);
    gboot(boot);
    u64 occv = 0, mycnt = 0;          // thread0-local, stable for whole kernel
    if (tid == 0) {
        int o = 0;
        for (int i = 0; i < 8; i++)
            if (__hip_atomic_load(&xcnt[i * 16], __ATOMIC_RELAXED, __HIP_MEMORY_SCOPE_AGENT)) o++;
        occv = (u64)o;
        mycnt = __hip_atomic_load(&xcnt[xcc * 16], __ATOMIC_RELAXED, __HIP_MEMORY_SCOPE_AGENT);
    }

    // ---- phase-1 swizzled tile mapping (r6) ----
    const int x8 = bid & 7;
    const int q  = bid >> 3;
    const int ct_ = x8 * 16 + (q & 15);
    const int yt  = q >> 4;
    const int u0 = ct_ * 8;
    const int rowbase = yt * 64;

    // ---- staging maps (phase 1) ----
    const int sr = tid >> 2;
    const int sk0 = (tid & 3) * 8;
    const int lb_k = tid >> 3;
    const int lb_c4 = (tid & 7) * 4;
    const int lb_gate = lb_c4 >> 3;
    const int lb_uoff = lb_c4 & 7;
    const int lb_coff = lb_gate * UNITSn + u0 + lb_uoff;

    // ---- MFMA lane mapping ----
    const int lane = tid & 63;
    const int rs = (tid >> 6) * 16;
    const int ml = lane & 15;
    const int kl = lane >> 4;

    // ---- self-calibrate C/D layout ----
    d4 zero4 = {0.0, 0.0, 0.0, 0.0};
    double onek0 = (kl == 0) ? 1.0 : 0.0;
    double mk0   = (kl == 0) ? (double)ml : 0.0;
    d4 prow = __builtin_amdgcn_mfma_f64_16x16x4f64(mk0, onek0, zero4, 0, 0, 0);
    d4 pcol = __builtin_amdgcn_mfma_f64_16x16x4f64(onek0, mk0, zero4, 0, 0, 0);
    int zoff[4];
    #pragma unroll
    for (int r = 0; r < 4; r++)
        zoff[r] = (rs + (int)prow[r]) * 33 + (int)pcol[r];

    // ---- epilogue maps ----
    const int eu = tid & 7;
    const int rr = tid >> 3;
    const int ug = u0 + eu;
    const double bi0 = (double)bias[ug];
    const double bf0 = (double)bias[UNITSn + ug];
    const double bc0 = (double)bias[2 * UNITSn + ug];
    const double bo0 = (double)bias[3 * UNITSn + ug];
    double creg[2] = {0.0, 0.0};

    // ---- phase-2 maps: 8 colT(64) x 64 rowT(4); stage: h 4x64, W 64x64 ----
    const int p2cb = (bid & 7) * 64;
    const int p2rb = (bid >> 3) * 4;
    const int p2wv = tid >> 6;
    const int p2ln = tid & 63;
    const int h_r = tid >> 6;          // 0..3
    const int h_k = tid & 63;          // 0..63
    const int w_k = tid >> 2;          // 0..63
    const int w_j = (tid & 3) * 16;    // 0,16,32,48
    const double bo2 = (double)bout[p2cb + p2ln];
    // phase-2 LDS (aliases smem): Hs 2x[64*5] dbl, Ws 2x[64*68] f32 = 39.9 KB
    double* Hs0 = smem;
    double* Hs1 = smem + 320;
    float*  Ws0 = (float*)(smem + 640);
    float*  Ws1 = Ws0 + 64 * 68;

    for (int t = 0; t < Tn; t++) {
        const double* hin = (t & 1) ? h1buf : h0buf;
        double* hout      = (t & 1) ? h0buf : h1buf;
        const u64* sprev  = (t & 1) ? slots0 : slots1;
        u64* scur         = (t & 1) ? slots1 : slots0;

        if (ct_ == 0 && tid < 64) scur[rowbase + tid] = 0ull;

        // ---- epilogue slot prefetch: issue NOW, consume after K-loop ----
        u64 spre0 = 0, spre1 = 0;
        if (t > 0) {
            spre0 = __hip_atomic_load((u64*)&sprev[rowbase + rr], __ATOMIC_RELAXED,
                                      __HIP_MEMORY_SCOPE_AGENT);
            spre1 = __hip_atomic_load((u64*)&sprev[rowbase + rr + 32], __ATOMIC_RELAXED,
                                      __HIP_MEMORY_SCOPE_AGENT);
        }

        const float* xrow = x + (size_t)(rowbase + sr) * (Tn * Dn) + (size_t)t * Dn;
        const double* hrow = hin + (size_t)(rowbase + sr) * UNITSn;

        double apfE[8]; float4 bpfE;
        double apfO[8]; float4 bpfO;

        auto prefetch = [&](int it, double (&apf)[8], float4& bpf) {
            int k0 = it * 32 + sk0;
            if (k0 < Dn) {
                float4 v0 = *(const float4*)(xrow + k0);
                float4 v1 = *(const float4*)(xrow + k0 + 4);
                apf[0] = (double)v0.x; apf[1] = (double)v0.y;
                apf[2] = (double)v0.z; apf[3] = (double)v0.w;
                apf[4] = (double)v1.x; apf[5] = (double)v1.y;
                apf[6] = (double)v1.z; apf[7] = (double)v1.w;
            } else {
                const double* hp = hrow + (k0 - Dn);
                double2 a = *(const double2*)(hp + 0);
                double2 b = *(const double2*)(hp + 2);
                double2 c2 = *(const double2*)(hp + 4);
                double2 d = *(const double2*)(hp + 6);
                apf[0] = a.x; apf[1] = a.y; apf[2] = b.x; apf[3] = b.y;
                apf[4] = c2.x; apf[5] = c2.y; apf[6] = d.x; apf[7] = d.y;
            }
            int kB = it * 32 + lb_k;
            const float* rowp = (kB < Dn) ? (W + (size_t)kB * G4n)
                                          : (U + (size_t)(kB - Dn) * G4n);
            bpf = *(const float4*)(rowp + lb_coff);
        };
        auto store_tiles = [&](int p, const double (&apf)[8], const float4& bpf) {
            double* As = smem + p * AS_TILE;
            double* Bs = smem + 2 * AS_TILE + p * BS_TILE;
            #pragma unroll
            for (int j = 0; j < 8; j += 2) {
                double2 w2; w2.x = apf[j]; w2.y = apf[j + 1];
                *(double2*)&As[sr * AS_STR + sk0 + j] = w2;
            }
            double2 w0; w0.x = (double)bpf.x; w0.y = (double)bpf.y;
            double2 w1; w1.x = (double)bpf.z; w1.y = (double)bpf.w;
            *(double2*)&Bs[lb_k * BS_STR + lb_c4] = w0;
            *(double2*)&Bs[lb_k * BS_STR + lb_c4 + 2] = w1;
        };

        d4 acc[2];
        acc[0] = zero4; acc[1] = zero4;

        auto do_mfma = [&](int p) {
            const double* As = smem + p * AS_TILE;
            const double* Bs = smem + 2 * AS_TILE + p * BS_TILE;
            __builtin_amdgcn_s_setprio(1);
            #pragma unroll
            for (int kq = 0; kq < 8; kq++) {
                double a = As[(rs + ml) * AS_STR + kq * 4 + kl];
                double b0 = Bs[(kq * 4 + kl) * BS_STR + ml];
                double b1 = Bs[(kq * 4 + kl) * BS_STR + 16 + ml];
                acc[0] = __builtin_amdgcn_mfma_f64_16x16x4f64(a, b0, acc[0], 0, 0, 0);
                acc[1] = __builtin_amdgcn_mfma_f64_16x16x4f64(a, b1, acc[1], 0, 0, 0);
            }
            __builtin_amdgcn_s_setprio(0);
        };

        // ---- 2-deep pipelined K loop; ds_writes BEFORE the MFMA cluster so the
        //      lgkm tail drains under the 1024-cy MFMA burst ----
        prefetch(0, apfE, bpfE);
        prefetch(1, apfO, bpfO);
        store_tiles(0, apfE, bpfE);
        BARLDS();

        for (int itp = 0; itp < NT; itp += 2) {
            if (itp + 2 < NT) prefetch(itp + 2, apfE, bpfE);
            store_tiles(1, apfO, bpfO);
            do_mfma(0);
            BARLDS();
            if (itp + 3 < NT) prefetch(itp + 3, apfO, bpfO);
            if (itp + 2 < NT) store_tiles(0, apfE, bpfE);
            do_mfma(1);
            BARLDS();
        }

        // ---- gate exchange: zex[64][33] aliases As0 ----
        double* zex = smem;
        #pragma unroll
        for (int r = 0; r < 4; r++) {
            zex[zoff[r]] = acc[0][r];
            zex[zoff[r] + 16] = acc[1][r];
        }
        __syncthreads();

        // ---- epilogue: batch the wrow gathers (idx known from prefetched slots) ----
        float wi0 = 0.f, wf0 = 0.f, wc0 = 0.f, wo0 = 0.f;
        float wi1 = 0.f, wf1 = 0.f, wc1 = 0.f, wo1 = 0.f;
        if (t > 0) {
            int idx0 = 1023 - (int)(spre0 & 1023ull);
            int idx1 = 1023 - (int)(spre1 & 1023ull);
            const float* wr0 = W + (size_t)(Dn + idx0) * G4n + ug;
            const float* wr1 = W + (size_t)(Dn + idx1) * G4n + ug;
            wi0 = wr0[0]; wf0 = wr0[UNITSn]; wc0 = wr0[2 * UNITSn]; wo0 = wr0[3 * UNITSn];
            wi1 = wr1[0]; wf1 = wr1[UNITSn]; wc1 = wr1[2 * UNITSn]; wo1 = wr1[3 * UNITSn];
            if (ct_ == 0 && eu == 0) {
                out[(size_t)(rowbase + rr) * Tn + (t - 1)] = idx0;
                out[(size_t)(rowbase + rr + 32) * Tn + (t - 1)] = idx1;
            }
        }
        #pragma unroll
        for (int s = 0; s < 2; s++) {
            int r = rr + 32 * s;
            int row = rowbase + r;
            double zi = zex[r * 33 + eu]      + bi0 + (double)(s ? wi1 : wi0);
            double zf = zex[r * 33 + 8 + eu]  + bf0 + (double)(s ? wf1 : wf0);
            double zc = zex[r * 33 + 16 + eu] + bc0 + (double)(s ? wc1 : wc0);
            double zo = zex[r * 33 + 24 + eu] + bo0 + (double)(s ? wo1 : wo0);
            double cold = creg[s];
            double ig = hsigd(zi), fg = hsigd(zf), og = hsigd(zo);
            double cn = fg * cold + ig * tanh(zc);
            double hn = og * tanh(cn);
            creg[s] = cn;
            hout[(size_t)row * UNITSn + ug] = hn;
        }

        // ---- gbar1: h(t) publish. Release (wbl2) by LAST block per XCD only
        //      (8/step instead of 512); per-block acquire (inv) kept: it is what
        //      refreshes every CU's L1+L2 (correctness per r6 audit). ----
        __syncthreads();
        if (tid == 0) {
            u64 o = __hip_atomic_fetch_add(&leafx[xcc * 16], 1ull,
                                           __ATOMIC_RELAXED, __HIP_MEMORY_SCOPE_AGENT);
            if (o == mycnt * (u64)(t + 1) - 1ull)
                __hip_atomic_fetch_add(root1, 1ull, __ATOMIC_RELEASE, __HIP_MEMORY_SCOPE_AGENT);
            int n = 0;
            while (__hip_atomic_load(root1, __ATOMIC_RELAXED, __HIP_MEMORY_SCOPE_AGENT)
                   < occv * (u64)(t + 1)) {
                __builtin_amdgcn_s_sleep(2);
                if (++n > 50000) break;
            }
            (void)__hip_atomic_load(root1, __ATOMIC_ACQUIRE, __HIP_MEMORY_SCOPE_AGENT);
        }
        __syncthreads();

        // ---- phase 2: pipelined logits tile (4 rows x 64 cols), 64-k double-buffer ----
        {
            double hA; float4 wA[4];
            double hB; float4 wB[4];
            auto p2load = [&](int kb, double& hr, float4 (&wr)[4]) {
                hr = hout[(size_t)(p2rb + h_r) * UNITSn + kb + h_k];
                const float* wp = Wout + (size_t)(kb + w_k) * NCn + p2cb + w_j;
                wr[0] = *(const float4*)(wp);
                wr[1] = *(const float4*)(wp + 4);
                wr[2] = *(const float4*)(wp + 8);
                wr[3] = *(const float4*)(wp + 12);
            };
            auto p2store = [&](double* H, float* Wl, double hr, const float4 (&wr)[4]) {
                H[h_k * 5 + h_r] = hr;
                *(float4*)&Wl[w_k * 68 + w_j]      = wr[0];
                *(float4*)&Wl[w_k * 68 + w_j + 4]  = wr[1];
                *(float4*)&Wl[w_k * 68 + w_j + 8]  = wr[2];
                *(float4*)&Wl[w_k * 68 + w_j + 12] = wr[3];
            };
            double acA = 0.0, acB = 0.0;
            auto p2comp = [&](const double* H, const float* Wl) {
                #pragma unroll
                for (int kk = 0; kk < 64; kk += 2) {
                    acA = fma(H[kk * 5 + p2wv], (double)Wl[kk * 68 + p2ln], acA);
                    acB = fma(H[(kk + 1) * 5 + p2wv], (double)Wl[(kk + 1) * 68 + p2ln], acB);
                }
            };

            p2load(0, hA, wA);
            p2store(Hs0, Ws0, hA, wA);
            p2load(64, hB, wB);
            __syncthreads();
            for (int kb2 = 0; kb2 < 1024; kb2 += 128) {
                if (kb2 + 128 < 1024) p2load(kb2 + 128, hA, wA);
                p2store(Hs1, Ws1, hB, wB);
                p2comp(Hs0, Ws0);
                __syncthreads();
                if (kb2 + 192 < 1024) p2load(kb2 + 192, hB, wB);
                if (kb2 + 128 < 1024) p2store(Hs0, Ws0, hA, wA);
                p2comp(Hs1, Ws1);
                __syncthreads();
            }
            double lg = acA + acB + bo2;
            u64 best = packlc(lg, p2cb + p2ln);
            #pragma unroll
            for (int m = 32; m >= 1; m >>= 1) {
                u64 o = __shfl_xor(best, m, 64);
                if (o > best) best = o;
            }
            if (p2ln == 0) atomicMax(&scur[p2rb + p2wv], best);
        }

        // ---- gbar2: slots(t) performed; no cache ops (device-scope atomics) ----
        __syncthreads();
        if (tid == 0) {
            u64 o = __hip_atomic_fetch_add(&leaves2[leaf * 16], 1ull,
                                           __ATOMIC_RELAXED, __HIP_MEMORY_SCOPE_AGENT);
            if (o == 8ull * (u64)(t + 1) - 1ull)
                __hip_atomic_fetch_add(root2, 1ull, __ATOMIC_RELAXED, __HIP_MEMORY_SCOPE_AGENT);
            int n = 0;
            while (__hip_atomic_load(root2, __ATOMIC_RELAXED, __HIP_MEMORY_SCOPE_AGENT)
                   < 64ull * (u64)(t + 1)) {
                __builtin_amdgcn_s_sleep(2);
                if (++n > 50000) break;
            }
        }
        __syncthreads();
    }

    // t = T-1 = 255 (odd) -> slots1; read L2-bypass (coherent point)
    if (bid == 0) {
        u64 s = __hip_atomic_load((u64*)&slots1[tid], __ATOMIC_RELAXED,
                                  __HIP_MEMORY_SCOPE_AGENT);
        out[(size_t)tid * Tn + (Tn - 1)] = 1023 - (int)(s & 1023ull);
    }
}

// ---------------- fallback path (small workspace): proven multi-launch kernels ------
__global__ __launch_bounds__(256, 2) void lstm_step(
    const float* __restrict__ x, const float* __restrict__ W,
    const float* __restrict__ U, const float* __restrict__ bias,
    const double* __restrict__ hin, double* __restrict__ hout,
    double* __restrict__ cst,
    const u64* __restrict__ slots_prev, u64* __restrict__ slots_cur,
    int* __restrict__ out, int t)
{
    __shared__ __align__(16) double smem[6144];

    const int tid = threadIdx.x;
    const int bid = blockIdx.x;
    const int ut = bid & 127;
    const int yt = bid >> 7;
    const int u0 = ut * 8;
    const int rowbase = yt * 64;

    if (ut == 0 && tid < 64) slots_cur[rowbase + tid] = 0ull;

    const int la_row = tid >> 2;
    const int la_k0 = (tid & 3) * 8;
    const int lb_k  = tid >> 3;
    const int lb_c4 = (tid & 7) * 4;
    const int lb_gate = lb_c4 >> 3;
    const int lb_uoff = lb_c4 & 7;

    const float* xrow = x + (size_t)(rowbase + la_row) * (Tn * Dn) + (size_t)t * Dn;
    const double* hrow = hin + (size_t)(rowbase + la_row) * UNITSn;

    double a_pf[8];
    double b_pf[4];

    auto prefetch = [&](int it) {
        int kg = it * 32;
        int k0 = kg + la_k0;
        if (k0 < Dn) {
            float4 v0 = *(const float4*)(xrow + k0);
            float4 v1 = *(const float4*)(xrow + k0 + 4);
            a_pf[0] = (double)v0.x; a_pf[1] = (double)v0.y;
            a_pf[2] = (double)v0.z; a_pf[3] = (double)v0.w;
            a_pf[4] = (double)v1.x; a_pf[5] = (double)v1.y;
            a_pf[6] = (double)v1.z; a_pf[7] = (double)v1.w;
        } else {
            const double* hp = hrow + (k0 - Dn);
            double2 h0v = *(const double2*)(hp + 0);
            double2 h1v = *(const double2*)(hp + 2);
            double2 h2v = *(const double2*)(hp + 4);
            double2 h3v = *(const double2*)(hp + 6);
            a_pf[0] = h0v.x; a_pf[1] = h0v.y; a_pf[2] = h1v.x; a_pf[3] = h1v.y;
            a_pf[4] = h2v.x; a_pf[5] = h2v.y; a_pf[6] = h3v.x; a_pf[7] = h3v.y;
        }
        int kB = kg + lb_k;
        const float* rowp = (kB < Dn) ? (W + (size_t)kB * G4n)
                                      : (U + (size_t)(kB - Dn) * G4n);
        float4 wv = *(const float4*)(rowp + lb_gate * UNITSn + u0 + lb_uoff);
        b_pf[0] = (double)wv.x; b_pf[1] = (double)wv.y;
        b_pf[2] = (double)wv.z; b_pf[3] = (double)wv.w;
    };
    auto store_tiles = [&](int p) {
        double* As = smem + p * 2048;
        double* Bs = smem + 4096 + p * 1024;
        #pragma unroll
        for (int j = 0; j < 8; j++) As[(la_k0 + j) * 64 + la_row] = a_pf[j];
        double2 w0; w0.x = b_pf[0]; w0.y = b_pf[1];
        double2 w1; w1.x = b_pf[2]; w1.y = b_pf[3];
        *(double2*)&Bs[lb_k * 32 + lb_c4] = w0;
        *(double2*)&Bs[lb_k * 32 + lb_c4 + 2] = w1;
    };

    const int lane = tid & 63;
    const int wv_ = tid >> 6;
    const int ri = lane >> 3;
    const int cj = lane & 7;
    const int rb = wv_ * 16 + ri * 2;

    double acc[2][4];
    #pragma unroll
    for (int i = 0; i < 2; i++)
        #pragma unroll
        for (int j = 0; j < 4; j++) acc[i][j] = 0.0;

    prefetch(0);
    store_tiles(0);
    __syncthreads();

    int p = 0;
    for (int it = 0; it < NT; it++) {
        if (it + 1 < NT) prefetch(it + 1);
        {
            const double* As = smem + p * 2048;
            const double* Bs = smem + 4096 + p * 1024;
            #pragma unroll
            for (int k = 0; k < 32; k++) {
                double2 a2 = *(const double2*)&As[k * 64 + rb];
                double2 b0 = *(const double2*)&Bs[k * 32 + cj * 4];
                double2 b1 = *(const double2*)&Bs[k * 32 + cj * 4 + 2];
                acc[0][0] = fma(a2.x, b0.x, acc[0][0]);
                acc[0][1] = fma(a2.x, b0.y, acc[0][1]);
                acc[0][2] = fma(a2.x, b1.x, acc[0][2]);
                acc[0][3] = fma(a2.x, b1.y, acc[0][3]);
                acc[1][0] = fma(a2.y, b0.x, acc[1][0]);
                acc[1][1] = fma(a2.y, b0.y, acc[1][1]);
                acc[1][2] = fma(a2.y, b1.x, acc[1][2]);
                acc[1][3] = fma(a2.y, b1.y, acc[1][3]);
            }
        }
        if (it + 1 < NT) store_tiles(p ^ 1);
        __syncthreads();
        p ^= 1;
    }

    double* zex = smem;
    #pragma unroll
    for (int i = 0; i < 2; i++) {
        double2 z0; z0.x = acc[i][0]; z0.y = acc[i][1];
        double2 z1; z1.x = acc[i][2]; z1.y = acc[i][3];
        *(double2*)&zex[(rb + i) * 32 + cj * 4] = z0;
        *(double2*)&zex[(rb + i) * 32 + cj * 4 + 2] = z1;
    }
    __syncthreads();

    const int eu = tid & 7;
    const int rr = tid >> 3;
    const int ug = u0 + eu;
    const double bi0 = (double)bias[ug];
    const double bf0 = (double)bias[UNITSn + ug];
    const double bc0 = (double)bias[2 * UNITSn + ug];
    const double bo0 = (double)bias[3 * UNITSn + ug];

    #pragma unroll
    for (int s = 0; s < 2; s++) {
        int r = rr + 32 * s;
        int row = rowbase + r;
        double zi = zex[r * 32 + eu]      + bi0;
        double zf = zex[r * 32 + 8 + eu]  + bf0;
        double zc = zex[r * 32 + 16 + eu] + bc0;
        double zo = zex[r * 32 + 24 + eu] + bo0;
        if (t > 0) {
            u64 sp = slots_prev[row];
            int idx = 1023 - (int)(sp & 1023ull);
            const float* wrow = W + (size_t)(Dn + idx) * G4n + ug;
            zi += (double)wrow[0];
            zf += (double)wrow[UNITSn];
            zc += (double)wrow[2 * UNITSn];
            zo += (double)wrow[3 * UNITSn];
            if (ut == 0 && eu == 0) out[(size_t)row * Tn + (t - 1)] = idx;
        }
        size_t off = (size_t)row * UNITSn + ug;
        double cold = cst[off];
        double ig = hsigd(zi), fg = hsigd(zf), og = hsigd(zo);
        double cn = fg * cold + ig * tanh(zc);
        double hn = og * tanh(cn);
        cst[off] = cn;
        hout[off] = hn;
    }
}

#define C_RT 8
#define C_CT 64
#define C_KC 32

__global__ __launch_bounds__(256) void logits_argmax(
    const double* __restrict__ h, const float* __restrict__ Wout,
    const float* __restrict__ bout, u64* __restrict__ slots)
{
    __shared__ double Hs[C_KC][9];
    __shared__ float  Ws[C_KC][C_CT];

    const int tid = threadIdx.x;
    const int ty = tid >> 5;
    const int tx = tid & 31;
    const int rbase = blockIdx.y * C_RT;
    const int cbase = blockIdx.x * C_CT;

    double acc0 = 0.0, acc1 = 0.0;

    const int lh_row = tid >> 5;
    const int lh_kk = tid & 31;
    const int lw_kk = tid >> 4;
    const int lw_j0 = (tid & 15) * 4;

    for (int kb = 0; kb < UNITSn; kb += C_KC) {
        Hs[lh_kk][lh_row] = h[(size_t)(rbase + lh_row) * UNITSn + kb + lh_kk];
        #pragma unroll
        for (int it = 0; it < 2; it++) {
            int kk = lw_kk + it * 16;
            float4 v = *(const float4*)(Wout + (size_t)(kb + kk) * NCn + cbase + lw_j0);
            *(float4*)&Ws[kk][lw_j0] = v;
        }
        __syncthreads();
        #pragma unroll
        for (int kk = 0; kk < C_KC; kk++) {
            double a = Hs[kk][ty];
            float2 wv = *(const float2*)&Ws[kk][tx * 2];
            acc0 = fma(a, (double)wv.x, acc0);
            acc1 = fma(a, (double)wv.y, acc1);
        }
        __syncthreads();
    }

    int col0 = cbase + tx * 2;
    double lg0 = acc0 + (double)bout[col0];
    double lg1 = acc1 + (double)bout[col0 + 1];

    u64 p0 = packlc(lg0, col0);
    u64 p1 = packlc(lg1, col0 + 1);
    u64 best = (p0 > p1) ? p0 : p1;
    #pragma unroll
    for (int off = 16; off >= 1; off >>= 1) {
        u64 o = __shfl_down(best, off, 32);
        if (o > best) best = o;
    }
    if (tx == 0) atomicMax(&slots[rbase + ty], best);
}

__global__ void final_decode(const u64* __restrict__ slots, int* __restrict__ out) {
    int b = threadIdx.x;
    u64 s = slots[b];
    out[(size_t)b * Tn + (Tn - 1)] = 1023 - (int)(s & 1023ull);
}

extern "C" void kernel_launch(void* const* d_in, const int* in_sizes, int n_in,
                              void* d_out, int out_size, void* d_ws, size_t ws_size,
                              hipStream_t stream) {
    const float* x    = (const float*)d_in[0];
    const float* W    = (const float*)d_in[1];
    const float* U    = (const float*)d_in[2];
    const float* bias = (const float*)d_in[3];
    const float* Wout = (const float*)d_in[4];
    const float* bout = (const float*)d_in[5];
    int* out = (int*)d_out;
    char* ws = (char*)d_ws;

    // ws layout: h0 2MB | h1 2MB | c 2MB (fallback) | slots0 @6MB | slots1 @+2048 |
    //            sync counters @+4096 (root1/root2/boot/xcnt/leafx/leaves2, ~11KB)
    double* h0 = (double*)(ws);
    double* h1 = (double*)(ws + (2u << 20));
    double* c  = (double*)(ws + (4u << 20));
    u64* slots0 = (u64*)(ws + (6u << 20));
    u64* slots1 = (u64*)(ws + (6u << 20) + 2048);
    u64* sync   = (u64*)(ws + (6u << 20) + 4096);

    const size_t NEED = (7ull << 20);
    const bool big = ws_size >= NEED;

    hipMemsetAsync(d_ws, 0, (6u << 20) + 32768, stream);

    if (big) {
        lstm_persistent<<<dim3(512), 256, 0, stream>>>(x, W, U, bias, Wout, bout,
                                                       h0, h1, slots0, slots1,
                                                       sync, out);
    } else {
        for (int t = 0; t < Tn; t++) {
            double* hin  = (t & 1) ? h1 : h0;
            double* hout = (t & 1) ? h0 : h1;
            u64* sprev = (t & 1) ? slots0 : slots1;
            u64* scur  = (t & 1) ? slots1 : slots0;
            lstm_step<<<dim3(512), 256, 0, stream>>>(x, W, U, bias, hin, hout, c,
                                                     sprev, scur, out, t);
            logits_argmax<<<dim3(8, 32), 256, 0, stream>>>(hout, Wout, bout, scur);
        }
        final_decode<<<1, Bn, 0, stream>>>(slots1, out);
    }
}

// Round 8
// 33865.570 us; speedup vs baseline: 1.5998x; 1.5998x over previous
//
#include <hip/hip_runtime.h>
#include <math.h>
#include <stdint.h>

#define Bn 256
#define Tn 256
#define Dn 512
#define UNITSn 1024
#define NCn 512
#define G4n 4096
#define KTn 1536   // 512 (x) + 1024 (h)
#define NT 48      // K tiles of 32

typedef unsigned long long u64;
typedef __attribute__((ext_vector_type(4))) double d4;

__device__ __forceinline__ double hsigd(double z) {
    return fmin(fmax(0.2 * z + 0.5, 0.0), 1.0);
}

// pack logit+col into u64: fixed-point (logit+2048)*2^40 (<<10) | (1023-col)
__device__ __forceinline__ u64 packlc(double v, int col) {
    double s = (v + 2048.0) * 1099511627776.0;   // 2^40
    u64 q = (u64)s;                              // < 2^53
    return (q << 10) | (u64)(1023 - col);
}

// ---------------- Kernel A (MFMA f64): z = [x|h]@[W;U] -> gates -> c,h ----------
// Multi-launch structure (proven 31.3 ms) + validated wins from the persistent arc:
//  - LDS stride 33 (odd): bank conflicts -9x [r3]
//  - fp32 B operand read straight from W/U, f64-converted in registers [r3]
//  - XCD-swizzled col tiles: per-XCD B slice 3MB -> within-step L2 reuse [r6]
//  - slot prefetch at kernel start + batched wrow gather in epilogue [r7]
#define AS_STR 33   // doubles per A row (k 0..31 + pad1)
#define BS_STR 33   // doubles per B k-row (32 cols + pad1)
#define AS_TILE (64 * AS_STR)    // 2112
#define BS_TILE (32 * BS_STR)    // 1056

__global__ __launch_bounds__(256, 2) void lstm_step_mfma(
    const float* __restrict__ x,
    const float* __restrict__ W, const float* __restrict__ U,
    const float* __restrict__ bias,
    const double* __restrict__ hin, double* __restrict__ hout,
    double* __restrict__ cst,
    const u64* __restrict__ slots_prev, u64* __restrict__ slots_cur,
    int* __restrict__ out, int t)
{
    // As0=0, As1=2112, Bs0=4224, Bs1=5280; total 6336 doubles = 50688 B -> 2 blk/CU.
    // zex[64][33] = 2112 doubles aliases As0 after the final barrier.
    __shared__ __align__(16) double smem[2 * AS_TILE + 2 * BS_TILE];

    const int tid = threadIdx.x;
    const int bid = blockIdx.x;
    // XCD swizzle: bid%8 = XCD (dispatch round-robin); XCD x owns col tiles
    // [16x, 16x+16) -> its W/U slice is 3MB (< 4MB L2), shared by its 64 blocks.
    const int ct_ = (bid & 7) * 16 + ((bid >> 3) & 15);   // col tile: 8 units
    const int yt  = bid >> 7;                             // row tile: 64 rows
    const int u0 = ct_ * 8;
    const int rowbase = yt * 64;

    if (ct_ == 0 && tid < 64) slots_cur[rowbase + tid] = 0ull;

    // ---- epilogue maps + slot prefetch (slots_prev complete before launch) ----
    const int eu = tid & 7;
    const int rr = tid >> 3;           // 0..31
    const int ug = u0 + eu;
    u64 spre0 = 0, spre1 = 0;
    if (t > 0) {
        spre0 = slots_prev[rowbase + rr];
        spre1 = slots_prev[rowbase + rr + 32];
    }

    // ---- staging maps ----
    const int sr = tid >> 2;                // A: row 0..63
    const int sk0 = (tid & 3) * 8;          // A: k base 0,8,16,24
    const int lb_k = tid >> 3;              // B: k 0..31
    const int lb_c4 = (tid & 7) * 4;        // B: col base 0,4,...,28
    const int lb_gate = lb_c4 >> 3;
    const int lb_uoff = lb_c4 & 7;          // 0 or 4
    const int lb_coff = lb_gate * UNITSn + u0 + lb_uoff;

    const float* xrow = x + (size_t)(rowbase + sr) * (Tn * Dn) + (size_t)t * Dn;
    const double* hrow = hin + (size_t)(rowbase + sr) * UNITSn;

    double apf[8];
    float4 bpf;

    auto prefetch = [&](int it) {
        int k0 = it * 32 + sk0;
        if (k0 < Dn) {
            float4 v0 = *(const float4*)(xrow + k0);
            float4 v1 = *(const float4*)(xrow + k0 + 4);
            apf[0] = (double)v0.x; apf[1] = (double)v0.y;
            apf[2] = (double)v0.z; apf[3] = (double)v0.w;
            apf[4] = (double)v1.x; apf[5] = (double)v1.y;
            apf[6] = (double)v1.z; apf[7] = (double)v1.w;
        } else {
            const double* hp = hrow + (k0 - Dn);
            double2 a = *(const double2*)(hp + 0);
            double2 b = *(const double2*)(hp + 2);
            double2 c2 = *(const double2*)(hp + 4);
            double2 d = *(const double2*)(hp + 6);
            apf[0] = a.x; apf[1] = a.y; apf[2] = b.x; apf[3] = b.y;
            apf[4] = c2.x; apf[5] = c2.y; apf[6] = d.x; apf[7] = d.y;
        }
        int kB = it * 32 + lb_k;
        const float* rowp = (kB < Dn) ? (W + (size_t)kB * G4n)
                                      : (U + (size_t)(kB - Dn) * G4n);
        bpf = *(const float4*)(rowp + lb_coff);
    };
    auto store_tiles = [&](int p) {
        double* As = smem + p * AS_TILE;
        double* Bs = smem + 2 * AS_TILE + p * BS_TILE;
        #pragma unroll
        for (int j = 0; j < 8; j += 2) {
            double2 w2; w2.x = apf[j]; w2.y = apf[j + 1];
            *(double2*)&As[sr * AS_STR + sk0 + j] = w2;
        }
        double2 w0; w0.x = (double)bpf.x; w0.y = (double)bpf.y;
        double2 w1; w1.x = (double)bpf.z; w1.y = (double)bpf.w;
        *(double2*)&Bs[lb_k * BS_STR + lb_c4] = w0;
        *(double2*)&Bs[lb_k * BS_STR + lb_c4 + 2] = w1;
    };

    // ---- MFMA lane mapping (A: m=lane%16,k=lane/16; B: n=lane%16,k=lane/16) ----
    const int lane = tid & 63;
    const int rs = (tid >> 6) * 16;    // row strip base
    const int ml = lane & 15;          // m / n within tile
    const int kl = lane >> 4;          // k within quad

    // ---- self-calibrate C/D layout via probe MFMAs (immune to layout errata) ----
    d4 zero4 = {0.0, 0.0, 0.0, 0.0};
    double onek0 = (kl == 0) ? 1.0 : 0.0;
    double mk0   = (kl == 0) ? (double)ml : 0.0;
    d4 prow = __builtin_amdgcn_mfma_f64_16x16x4f64(mk0, onek0, zero4, 0, 0, 0);
    d4 pcol = __builtin_amdgcn_mfma_f64_16x16x4f64(onek0, mk0, zero4, 0, 0, 0);
    int zoff[4];
    #pragma unroll
    for (int r = 0; r < 4; r++)
        zoff[r] = (rs + (int)prow[r]) * 33 + (int)pcol[r];

    d4 acc[2];
    acc[0] = zero4; acc[1] = zero4;

    prefetch(0);
    store_tiles(0);
    __syncthreads();

    int p = 0;
    for (int it = 0; it < NT; it++) {
        if (it + 1 < NT) prefetch(it + 1);
        {
            const double* As = smem + p * AS_TILE;
            const double* Bs = smem + 2 * AS_TILE + p * BS_TILE;
            #pragma unroll
            for (int kq = 0; kq < 8; kq++) {
                double a = As[(rs + ml) * AS_STR + kq * 4 + kl];
                double b0 = Bs[(kq * 4 + kl) * BS_STR + ml];
                double b1 = Bs[(kq * 4 + kl) * BS_STR + 16 + ml];
                acc[0] = __builtin_amdgcn_mfma_f64_16x16x4f64(a, b0, acc[0], 0, 0, 0);
                acc[1] = __builtin_amdgcn_mfma_f64_16x16x4f64(a, b1, acc[1], 0, 0, 0);
            }
        }
        if (it + 1 < NT) store_tiles(p ^ 1);
        __syncthreads();
        p ^= 1;
    }

    // ---- gate exchange: zex[64][33] aliases As0 (post-final-barrier) ----
    double* zex = smem;
    #pragma unroll
    for (int r = 0; r < 4; r++) {
        zex[zoff[r]] = acc[0][r];
        zex[zoff[r] + 16] = acc[1][r];
    }
    __syncthreads();

    // ---- epilogue: 2 cells/thread; wrow gathers batched from prefetched slots ----
    const double bi0 = (double)bias[ug];
    const double bf0 = (double)bias[UNITSn + ug];
    const double bc0 = (double)bias[2 * UNITSn + ug];
    const double bo0 = (double)bias[3 * UNITSn + ug];

    float wi0 = 0.f, wf0 = 0.f, wc0 = 0.f, wo0 = 0.f;
    float wi1 = 0.f, wf1 = 0.f, wc1 = 0.f, wo1 = 0.f;
    if (t > 0) {
        int idx0 = 1023 - (int)(spre0 & 1023ull);
        int idx1 = 1023 - (int)(spre1 & 1023ull);
        const float* wr0 = W + (size_t)(Dn + idx0) * G4n + ug;
        const float* wr1 = W + (size_t)(Dn + idx1) * G4n + ug;
        wi0 = wr0[0]; wf0 = wr0[UNITSn]; wc0 = wr0[2 * UNITSn]; wo0 = wr0[3 * UNITSn];
        wi1 = wr1[0]; wf1 = wr1[UNITSn]; wc1 = wr1[2 * UNITSn]; wo1 = wr1[3 * UNITSn];
        if (ct_ == 0 && eu == 0) {
            out[(size_t)(rowbase + rr) * Tn + (t - 1)] = idx0;
            out[(size_t)(rowbase + rr + 32) * Tn + (t - 1)] = idx1;
        }
    }
    #pragma unroll
    for (int s = 0; s < 2; s++) {
        int r = rr + 32 * s;
        int row = rowbase + r;
        double zi = zex[r * 33 + eu]      + bi0 + (double)(s ? wi1 : wi0);
        double zf = zex[r * 33 + 8 + eu]  + bf0 + (double)(s ? wf1 : wf0);
        double zc = zex[r * 33 + 16 + eu] + bc0 + (double)(s ? wc1 : wc0);
        double zo = zex[r * 33 + 24 + eu] + bo0 + (double)(s ? wo1 : wo0);
        size_t off = (size_t)row * UNITSn + ug;
        double cold = cst[off];
        double ig = hsigd(zi), fg = hsigd(zf), og = hsigd(zo);
        double cn = fg * cold + ig * tanh(zc);
        double hn = og * tanh(cn);
        cst[off] = cn;
        hout[off] = hn;
    }
}

// ---------------- Kernel C: logits = h@Wout + bout (fp64), fused argmax ----
// Unchanged from the proven 31.3 ms baseline.
#define C_RT 8
#define C_CT 64
#define C_KC 32

__global__ __launch_bounds__(256) void logits_argmax(
    const double* __restrict__ h, const float* __restrict__ Wout,
    const float* __restrict__ bout, u64* __restrict__ slots)
{
    __shared__ double Hs[C_KC][9];
    __shared__ float  Ws[C_KC][C_CT];

    const int tid = threadIdx.x;
    const int ty = tid >> 5;
    const int tx = tid & 31;
    const int rbase = blockIdx.y * C_RT;
    const int cbase = blockIdx.x * C_CT;

    double acc0 = 0.0, acc1 = 0.0;

    const int lh_row = tid >> 5;
    const int lh_kk = tid & 31;
    const int lw_kk = tid >> 4;
    const int lw_j0 = (tid & 15) * 4;

    for (int kb = 0; kb < UNITSn; kb += C_KC) {
        Hs[lh_kk][lh_row] = h[(size_t)(rbase + lh_row) * UNITSn + kb + lh_kk];
        #pragma unroll
        for (int it = 0; it < 2; it++) {
            int kk = lw_kk + it * 16;
            float4 v = *(const float4*)(Wout + (size_t)(kb + kk) * NCn + cbase + lw_j0);
            *(float4*)&Ws[kk][lw_j0] = v;
        }
        __syncthreads();
        #pragma unroll
        for (int kk = 0; kk < C_KC; kk++) {
            double a = Hs[kk][ty];
            float2 wv = *(const float2*)&Ws[kk][tx * 2];
            acc0 = fma(a, (double)wv.x, acc0);
            acc1 = fma(a, (double)wv.y, acc1);
        }
        __syncthreads();
    }

    int col0 = cbase + tx * 2;
    double lg0 = acc0 + (double)bout[col0];
    double lg1 = acc1 + (double)bout[col0 + 1];

    u64 p0 = packlc(lg0, col0);
    u64 p1 = packlc(lg1, col0 + 1);
    u64 best = (p0 > p1) ? p0 : p1;
    #pragma unroll
    for (int off = 16; off >= 1; off >>= 1) {
        u64 o = __shfl_down(best, off, 32);
        if (o > best) best = o;
    }
    if (tx == 0) atomicMax(&slots[rbase + ty], best);
}

// ---------------- final step decode ----------------
__global__ void final_decode(const u64* __restrict__ slots, int* __restrict__ out) {
    int b = threadIdx.x;
    u64 s = slots[b];
    out[(size_t)b * Tn + (Tn - 1)] = 1023 - (int)(s & 1023ull);
}

extern "C" void kernel_launch(void* const* d_in, const int* in_sizes, int n_in,
                              void* d_out, int out_size, void* d_ws, size_t ws_size,
                              hipStream_t stream) {
    const float* x    = (const float*)d_in[0];
    const float* W    = (const float*)d_in[1];
    const float* U    = (const float*)d_in[2];
    const float* bias = (const float*)d_in[3];
    const float* Wout = (const float*)d_in[4];
    const float* bout = (const float*)d_in[5];
    int* out = (int*)d_out;
    char* ws = (char*)d_ws;

    // ws layout: h0 (2MB) | h1 (2MB) | c (2MB) | slots0 @6MB | slots1 @+2048
    double* h0 = (double*)(ws);
    double* h1 = (double*)(ws + (2u << 20));
    double* c  = (double*)(ws + (4u << 20));
    u64* slots0 = (u64*)(ws + (6u << 20));
    u64* slots1 = (u64*)(ws + (6u << 20) + 2048);

    hipMemsetAsync(d_ws, 0, (6u << 20) + 8192, stream);

    for (int t = 0; t < Tn; t++) {
        double* hin  = (t & 1) ? h1 : h0;
        double* hout = (t & 1) ? h0 : h1;
        u64* sprev = (t & 1) ? slots0 : slots1;   // written by C(t-1)
        u64* scur  = (t & 1) ? slots1 : slots0;   // zeroed by A(t), written by C(t)
        lstm_step_mfma<<<dim3(512), 256, 0, stream>>>(x, W, U, bias, hin, hout, c,
                                                      sprev, scur, out, t);
        logits_argmax<<<dim3(8, 32), 256, 0, stream>>>(hout, Wout, bout, scur);
    }
    // t = T-1 = 255 (odd) -> its slots live in slots1
    final_decode<<<1, Bn, 0, stream>>>(slots1, out);
}

// Round 9
// 33266.302 us; speedup vs baseline: 1.6286x; 1.0180x over previous
//
#include <hip/hip_runtime.h>
#include <math.h>
#include <stdint.h>

#define Bn 256
#define Tn 256
#define Dn 512
#define UNITSn 1024
#define NCn 512
#define G4n 4096
#define KTn 1536   // 512 (x) + 1024 (h)
#define NT 48      // K tiles of 32

typedef unsigned long long u64;
typedef __attribute__((ext_vector_type(4))) double d4;

__device__ __forceinline__ double hsigd(double z) {
    return fmin(fmax(0.2 * z + 0.5, 0.0), 1.0);
}

// pack logit+col into u64: fixed-point (logit+2048)*2^40 (<<10) | (1023-col)
__device__ __forceinline__ u64 packlc(double v, int col) {
    double s = (v + 2048.0) * 1099511627776.0;   // 2^40
    u64 q = (u64)s;                              // < 2^53
    return (q << 10) | (u64)(1023 - col);
}

// ---------------- weight pre-conversion: Wd[k][4096] = fp64 of [Wx; U] ----------------
__global__ void convert_weights(const float* __restrict__ W, const float* __restrict__ U,
                                double* __restrict__ Wd)
{
    size_t stride = (size_t)gridDim.x * blockDim.x;
    for (size_t i = (size_t)blockIdx.x * blockDim.x + threadIdx.x;
         i < (size_t)KTn * G4n; i += stride) {
        int k = (int)(i >> 12);
        int j = (int)(i & 4095);
        float v = (k < Dn) ? W[i] : U[(size_t)(k - Dn) * G4n + j];
        Wd[i] = (double)v;
    }
}

// ---------------- Kernel A (MFMA f64): z = [x|h]@[Wx;U] -> gates -> c,h ----------
// EXACT baseline staging (proven 31.3 ms): Wd fp64 B (32B/thread, full-line pairs),
// stride 34 (16B-aligned b128 LDS stores; r3 proved its bank conflicts are not on
// the critical path). Added on top, each individually low-risk:
//  - XCD swizzle of col tiles (bid%8=XCD): L2 locality for the Wd slice [r6]
//  - slot prefetch at kernel start + batched wrow gather in epilogue [r7/r8]
//  - s_setprio(1) around the MFMA cluster (2 blocks/CU are phase-skewed)
#define AS_STR 34   // doubles per A row (k 0..31 + pad2)
#define BS_STR 34   // doubles per B k-row (32 cols + pad2)
#define AS_TILE (64 * AS_STR)    // 2176
#define BS_TILE (32 * BS_STR)    // 1088

__global__ __launch_bounds__(256, 2) void lstm_step_mfma(
    const float* __restrict__ x, const double* __restrict__ Wd,
    const float* __restrict__ W, const float* __restrict__ bias,
    const double* __restrict__ hin, double* __restrict__ hout,
    double* __restrict__ cst,
    const u64* __restrict__ slots_prev, u64* __restrict__ slots_cur,
    int* __restrict__ out, int t)
{
    // As0=0, As1=2176, Bs0=4352, Bs1=5440; total 6528 doubles = 52224 B -> 2 blk/CU.
    // zex[64][33] = 2112 doubles aliases As0 after the final barrier.
    __shared__ __align__(16) double smem[2 * AS_TILE + 2 * BS_TILE];

    const int tid = threadIdx.x;
    const int bid = blockIdx.x;
    // XCD swizzle: bid%8 = XCD (dispatch round-robin); XCD x owns col tiles
    // [16x, 16x+16) so its 64 blocks share one 6MB Wd slice (L2+L3 locality).
    const int ct_ = (bid & 7) * 16 + ((bid >> 3) & 15);   // col tile: 8 units
    const int yt  = bid >> 7;                             // row tile: 64 rows
    const int u0 = ct_ * 8;
    const int rowbase = yt * 64;

    if (ct_ == 0 && tid < 64) slots_cur[rowbase + tid] = 0ull;

    // ---- epilogue maps + slot prefetch (slots_prev complete before launch) ----
    const int eu = tid & 7;
    const int rr = tid >> 3;           // 0..31
    const int ug = u0 + eu;
    u64 spre0 = 0, spre1 = 0;
    if (t > 0) {
        spre0 = slots_prev[rowbase + rr];
        spre1 = slots_prev[rowbase + rr + 32];
    }

    // ---- staging maps ----
    const int sr = tid >> 2;                // A: row 0..63
    const int sk0 = (tid & 3) * 8;          // A: k base 0,8,16,24
    const int lb_k = tid >> 3;              // B: k 0..31
    const int lb_c4 = (tid & 7) * 4;        // B: col base 0,4,...,28
    const int lb_gate = lb_c4 >> 3;
    const int lb_uoff = lb_c4 & 7;          // 0 or 4

    const float* xrow = x + (size_t)(rowbase + sr) * (Tn * Dn) + (size_t)t * Dn;
    const double* hrow = hin + (size_t)(rowbase + sr) * UNITSn;
    const double* wb = Wd + (size_t)lb_gate * UNITSn + u0 + lb_uoff;

    double apf[8];
    double2 bpf[2];

    auto prefetch = [&](int it) {
        int k0 = it * 32 + sk0;
        if (k0 < Dn) {
            float4 v0 = *(const float4*)(xrow + k0);
            float4 v1 = *(const float4*)(xrow + k0 + 4);
            apf[0] = (double)v0.x; apf[1] = (double)v0.y;
            apf[2] = (double)v0.z; apf[3] = (double)v0.w;
            apf[4] = (double)v1.x; apf[5] = (double)v1.y;
            apf[6] = (double)v1.z; apf[7] = (double)v1.w;
        } else {
            const double* hp = hrow + (k0 - Dn);
            double2 a = *(const double2*)(hp + 0);
            double2 b = *(const double2*)(hp + 2);
            double2 c2 = *(const double2*)(hp + 4);
            double2 d = *(const double2*)(hp + 6);
            apf[0] = a.x; apf[1] = a.y; apf[2] = b.x; apf[3] = b.y;
            apf[4] = c2.x; apf[5] = c2.y; apf[6] = d.x; apf[7] = d.y;
        }
        const double* bp = wb + (size_t)(it * 32 + lb_k) * G4n;
        bpf[0] = *(const double2*)(bp);
        bpf[1] = *(const double2*)(bp + 2);
    };
    auto store_tiles = [&](int p) {
        double* As = smem + p * AS_TILE;
        double* Bs = smem + 2 * AS_TILE + p * BS_TILE;
        #pragma unroll
        for (int j = 0; j < 8; j += 2) {
            double2 w2; w2.x = apf[j]; w2.y = apf[j + 1];
            *(double2*)&As[sr * AS_STR + sk0 + j] = w2;
        }
        *(double2*)&Bs[lb_k * BS_STR + lb_c4] = bpf[0];
        *(double2*)&Bs[lb_k * BS_STR + lb_c4 + 2] = bpf[1];
    };

    // ---- MFMA lane mapping (A: m=lane%16,k=lane/16; B: n=lane%16,k=lane/16) ----
    const int lane = tid & 63;
    const int rs = (tid >> 6) * 16;    // row strip base
    const int ml = lane & 15;          // m / n within tile
    const int kl = lane >> 4;          // k within quad

    // ---- self-calibrate C/D layout via probe MFMAs (immune to layout errata) ----
    d4 zero4 = {0.0, 0.0, 0.0, 0.0};
    double onek0 = (kl == 0) ? 1.0 : 0.0;
    double mk0   = (kl == 0) ? (double)ml : 0.0;
    d4 prow = __builtin_amdgcn_mfma_f64_16x16x4f64(mk0, onek0, zero4, 0, 0, 0);
    d4 pcol = __builtin_amdgcn_mfma_f64_16x16x4f64(onek0, mk0, zero4, 0, 0, 0);
    int zoff[4];
    #pragma unroll
    for (int r = 0; r < 4; r++)
        zoff[r] = (rs + (int)prow[r]) * 33 + (int)pcol[r];

    d4 acc[2];
    acc[0] = zero4; acc[1] = zero4;

    prefetch(0);
    store_tiles(0);
    __syncthreads();

    int p = 0;
    for (int it = 0; it < NT; it++) {
        if (it + 1 < NT) prefetch(it + 1);
        {
            const double* As = smem + p * AS_TILE;
            const double* Bs = smem + 2 * AS_TILE + p * BS_TILE;
            __builtin_amdgcn_s_setprio(1);
            #pragma unroll
            for (int kq = 0; kq < 8; kq++) {
                double a = As[(rs + ml) * AS_STR + kq * 4 + kl];
                double b0 = Bs[(kq * 4 + kl) * BS_STR + ml];
                double b1 = Bs[(kq * 4 + kl) * BS_STR + 16 + ml];
                acc[0] = __builtin_amdgcn_mfma_f64_16x16x4f64(a, b0, acc[0], 0, 0, 0);
                acc[1] = __builtin_amdgcn_mfma_f64_16x16x4f64(a, b1, acc[1], 0, 0, 0);
            }
            __builtin_amdgcn_s_setprio(0);
        }
        if (it + 1 < NT) store_tiles(p ^ 1);
        __syncthreads();
        p ^= 1;
    }

    // ---- gate exchange: zex[64][33] aliases As0 (post-final-barrier) ----
    double* zex = smem;
    #pragma unroll
    for (int r = 0; r < 4; r++) {
        zex[zoff[r]] = acc[0][r];
        zex[zoff[r] + 16] = acc[1][r];
    }
    __syncthreads();

    // ---- epilogue: 2 cells/thread; wrow gathers batched from prefetched slots ----
    const double bi0 = (double)bias[ug];
    const double bf0 = (double)bias[UNITSn + ug];
    const double bc0 = (double)bias[2 * UNITSn + ug];
    const double bo0 = (double)bias[3 * UNITSn + ug];

    float wi0 = 0.f, wf0 = 0.f, wc0 = 0.f, wo0 = 0.f;
    float wi1 = 0.f, wf1 = 0.f, wc1 = 0.f, wo1 = 0.f;
    if (t > 0) {
        int idx0 = 1023 - (int)(spre0 & 1023ull);
        int idx1 = 1023 - (int)(spre1 & 1023ull);
        const float* wr0 = W + (size_t)(Dn + idx0) * G4n + ug;
        const float* wr1 = W + (size_t)(Dn + idx1) * G4n + ug;
        wi0 = wr0[0]; wf0 = wr0[UNITSn]; wc0 = wr0[2 * UNITSn]; wo0 = wr0[3 * UNITSn];
        wi1 = wr1[0]; wf1 = wr1[UNITSn]; wc1 = wr1[2 * UNITSn]; wo1 = wr1[3 * UNITSn];
        if (ct_ == 0 && eu == 0) {
            out[(size_t)(rowbase + rr) * Tn + (t - 1)] = idx0;
            out[(size_t)(rowbase + rr + 32) * Tn + (t - 1)] = idx1;
        }
    }
    #pragma unroll
    for (int s = 0; s < 2; s++) {
        int r = rr + 32 * s;
        int row = rowbase + r;
        double zi = zex[r * 33 + eu]      + bi0 + (double)(s ? wi1 : wi0);
        double zf = zex[r * 33 + 8 + eu]  + bf0 + (double)(s ? wf1 : wf0);
        double zc = zex[r * 33 + 16 + eu] + bc0 + (double)(s ? wc1 : wc0);
        double zo = zex[r * 33 + 24 + eu] + bo0 + (double)(s ? wo1 : wo0);
        size_t off = (size_t)row * UNITSn + ug;
        double cold = cst[off];
        double ig = hsigd(zi), fg = hsigd(zf), og = hsigd(zo);
        double cn = fg * cold + ig * tanh(zc);
        double hn = og * tanh(cn);
        cst[off] = cn;
        hout[off] = hn;
    }
}

// ---------------- Kernel C: logits = h@Wout + bout (fp64), fused argmax ----
// Doubled parallelism vs baseline: grid (8,64) = 512 blocks (2/CU), each block
// 4 rows x 64 cols. Wave w owns row rbase+w; full-wave shuffle argmax.
__global__ __launch_bounds__(256) void logits_argmax(
    const double* __restrict__ h, const float* __restrict__ Wout,
    const float* __restrict__ bout, u64* __restrict__ slots)
{
    __shared__ double Hs[32][5];
    __shared__ float  Ws[32][68];

    const int tid = threadIdx.x;
    const int row = tid >> 6;          // 0..3 (wave id)
    const int col = tid & 63;          // lane
    const int rbase = blockIdx.y * 4;
    const int cbase = blockIdx.x * 64;

    const int hr = tid >> 5;           // 0..7 (use <4 via tid<128)
    const int hk = tid & 31;
    const int wk = tid >> 3;           // 0..31
    const int wj = (tid & 7) * 8;      // 0,8,...,56

    double acc0 = 0.0, acc1 = 0.0;

    for (int kb = 0; kb < UNITSn; kb += 32) {
        if (tid < 128)
            Hs[hk][hr] = h[(size_t)(rbase + hr) * UNITSn + kb + hk];
        const float* wp = Wout + (size_t)(kb + wk) * NCn + cbase + wj;
        *(float4*)&Ws[wk][wj]     = *(const float4*)(wp);
        *(float4*)&Ws[wk][wj + 4] = *(const float4*)(wp + 4);
        __syncthreads();
        #pragma unroll
        for (int kk = 0; kk < 32; kk += 2) {
            acc0 = fma(Hs[kk][row],     (double)Ws[kk][col],     acc0);
            acc1 = fma(Hs[kk + 1][row], (double)Ws[kk + 1][col], acc1);
        }
        __syncthreads();
    }

    double lg = acc0 + acc1 + (double)bout[cbase + col];
    u64 best = packlc(lg, cbase + col);
    #pragma unroll
    for (int m = 32; m >= 1; m >>= 1) {
        u64 o = __shfl_xor(best, m, 64);
        if (o > best) best = o;
    }
    if (col == 0) atomicMax(&slots[rbase + row], best);
}

// ---------------- final step decode ----------------
__global__ void final_decode(const u64* __restrict__ slots, int* __restrict__ out) {
    int b = threadIdx.x;
    u64 s = slots[b];
    out[(size_t)b * Tn + (Tn - 1)] = 1023 - (int)(s & 1023ull);
}

// ---------------- fallback (small workspace): vector fp64 kernel A ----------
__global__ __launch_bounds__(256, 2) void lstm_step(
    const float* __restrict__ x, const float* __restrict__ W,
    const float* __restrict__ U, const float* __restrict__ bias,
    const double* __restrict__ hin, double* __restrict__ hout,
    double* __restrict__ cst,
    const u64* __restrict__ slots_prev, u64* __restrict__ slots_cur,
    int* __restrict__ out, int t)
{
    __shared__ __align__(16) double smem[6144];

    const int tid = threadIdx.x;
    const int bid = blockIdx.x;
    const int ut = bid & 127;
    const int yt = bid >> 7;
    const int u0 = ut * 8;
    const int rowbase = yt * 64;

    if (ut == 0 && tid < 64) slots_cur[rowbase + tid] = 0ull;

    const int la_row = tid >> 2;
    const int la_k0 = (tid & 3) * 8;
    const int lb_k  = tid >> 3;
    const int lb_c4 = (tid & 7) * 4;
    const int lb_gate = lb_c4 >> 3;
    const int lb_uoff = lb_c4 & 7;

    const float* xrow = x + (size_t)(rowbase + la_row) * (Tn * Dn) + (size_t)t * Dn;
    const double* hrow = hin + (size_t)(rowbase + la_row) * UNITSn;

    double a_pf[8];
    double b_pf[4];

    auto prefetch = [&](int it) {
        int kg = it * 32;
        int k0 = kg + la_k0;
        if (k0 < Dn) {
            float4 v0 = *(const float4*)(xrow + k0);
            float4 v1 = *(const float4*)(xrow + k0 + 4);
            a_pf[0] = (double)v0.x; a_pf[1] = (double)v0.y;
            a_pf[2] = (double)v0.z; a_pf[3] = (double)v0.w;
            a_pf[4] = (double)v1.x; a_pf[5] = (double)v1.y;
            a_pf[6] = (double)v1.z; a_pf[7] = (double)v1.w;
        } else {
            const double* hp = hrow + (k0 - Dn);
            double2 h0v = *(const double2*)(hp + 0);
            double2 h1v = *(const double2*)(hp + 2);
            double2 h2v = *(const double2*)(hp + 4);
            double2 h3v = *(const double2*)(hp + 6);
            a_pf[0] = h0v.x; a_pf[1] = h0v.y; a_pf[2] = h1v.x; a_pf[3] = h1v.y;
            a_pf[4] = h2v.x; a_pf[5] = h2v.y; a_pf[6] = h3v.x; a_pf[7] = h3v.y;
        }
        int kB = kg + lb_k;
        const float* rowp = (kB < Dn) ? (W + (size_t)kB * G4n)
                                      : (U + (size_t)(kB - Dn) * G4n);
        float4 wv = *(const float4*)(rowp + lb_gate * UNITSn + u0 + lb_uoff);
        b_pf[0] = (double)wv.x; b_pf[1] = (double)wv.y;
        b_pf[2] = (double)wv.z; b_pf[3] = (double)wv.w;
    };
    auto store_tiles = [&](int p) {
        double* As = smem + p * 2048;
        double* Bs = smem + 4096 + p * 1024;
        #pragma unroll
        for (int j = 0; j < 8; j++) As[(la_k0 + j) * 64 + la_row] = a_pf[j];
        double2 w0; w0.x = b_pf[0]; w0.y = b_pf[1];
        double2 w1; w1.x = b_pf[2]; w1.y = b_pf[3];
        *(double2*)&Bs[lb_k * 32 + lb_c4] = w0;
        *(double2*)&Bs[lb_k * 32 + lb_c4 + 2] = w1;
    };

    const int lane = tid & 63;
    const int wv_ = tid >> 6;
    const int ri = lane >> 3;
    const int cj = lane & 7;
    const int rb = wv_ * 16 + ri * 2;

    double acc[2][4];
    #pragma unroll
    for (int i = 0; i < 2; i++)
        #pragma unroll
        for (int j = 0; j < 4; j++) acc[i][j] = 0.0;

    prefetch(0);
    store_tiles(0);
    __syncthreads();

    int p = 0;
    for (int it = 0; it < NT; it++) {
        if (it + 1 < NT) prefetch(it + 1);
        {
            const double* As = smem + p * 2048;
            const double* Bs = smem + 4096 + p * 1024;
            #pragma unroll
            for (int k = 0; k < 32; k++) {
                double2 a2 = *(const double2*)&As[k * 64 + rb];
                double2 b0 = *(const double2*)&Bs[k * 32 + cj * 4];
                double2 b1 = *(const double2*)&Bs[k * 32 + cj * 4 + 2];
                acc[0][0] = fma(a2.x, b0.x, acc[0][0]);
                acc[0][1] = fma(a2.x, b0.y, acc[0][1]);
                acc[0][2] = fma(a2.x, b1.x, acc[0][2]);
                acc[0][3] = fma(a2.x, b1.y, acc[0][3]);
                acc[1][0] = fma(a2.y, b0.x, acc[1][0]);
                acc[1][1] = fma(a2.y, b0.y, acc[1][1]);
                acc[1][2] = fma(a2.y, b1.x, acc[1][2]);
                acc[1][3] = fma(a2.y, b1.y, acc[1][3]);
            }
        }
        if (it + 1 < NT) store_tiles(p ^ 1);
        __syncthreads();
        p ^= 1;
    }

    double* zex = smem;
    #pragma unroll
    for (int i = 0; i < 2; i++) {
        double2 z0; z0.x = acc[i][0]; z0.y = acc[i][1];
        double2 z1; z1.x = acc[i][2]; z1.y = acc[i][3];
        *(double2*)&zex[(rb + i) * 32 + cj * 4] = z0;
        *(double2*)&zex[(rb + i) * 32 + cj * 4 + 2] = z1;
    }
    __syncthreads();

    const int eu = tid & 7;
    const int rr = tid >> 3;
    const int ug = u0 + eu;
    const double bi0 = (double)bias[ug];
    const double bf0 = (double)bias[UNITSn + ug];
    const double bc0 = (double)bias[2 * UNITSn + ug];
    const double bo0 = (double)bias[3 * UNITSn + ug];

    #pragma unroll
    for (int s = 0; s < 2; s++) {
        int r = rr + 32 * s;
        int row = rowbase + r;
        double zi = zex[r * 32 + eu]      + bi0;
        double zf = zex[r * 32 + 8 + eu]  + bf0;
        double zc = zex[r * 32 + 16 + eu] + bc0;
        double zo = zex[r * 32 + 24 + eu] + bo0;
        if (t > 0) {
            u64 sp = slots_prev[row];
            int idx = 1023 - (int)(sp & 1023ull);
            const float* wrow = W + (size_t)(Dn + idx) * G4n + ug;
            zi += (double)wrow[0];
            zf += (double)wrow[UNITSn];
            zc += (double)wrow[2 * UNITSn];
            zo += (double)wrow[3 * UNITSn];
            if (ut == 0 && eu == 0) out[(size_t)row * Tn + (t - 1)] = idx;
        }
        size_t off = (size_t)row * UNITSn + ug;
        double cold = cst[off];
        double ig = hsigd(zi), fg = hsigd(zf), og = hsigd(zo);
        double cn = fg * cold + ig * tanh(zc);
        double hn = og * tanh(cn);
        cst[off] = cn;
        hout[off] = hn;
    }
}

extern "C" void kernel_launch(void* const* d_in, const int* in_sizes, int n_in,
                              void* d_out, int out_size, void* d_ws, size_t ws_size,
                              hipStream_t stream) {
    const float* x    = (const float*)d_in[0];
    const float* W    = (const float*)d_in[1];
    const float* U    = (const float*)d_in[2];
    const float* bias = (const float*)d_in[3];
    const float* Wout = (const float*)d_in[4];
    const float* bout = (const float*)d_in[5];
    int* out = (int*)d_out;
    char* ws = (char*)d_ws;

    // ws layout: h0 (2MB) | h1 (2MB) | c (2MB) | slots0/1 (4KB) | Wd 48MB @8MB
    double* h0 = (double*)(ws);
    double* h1 = (double*)(ws + (2u << 20));
    double* c  = (double*)(ws + (4u << 20));
    u64* slots0 = (u64*)(ws + (6u << 20));
    u64* slots1 = (u64*)(ws + (6u << 20) + 2048);
    double* Wd  = (double*)(ws + (8u << 20));

    const size_t NEED = (8ull << 20) + (size_t)KTn * G4n * 8;
    const bool big = ws_size >= NEED;

    hipMemsetAsync(d_ws, 0, (6u << 20) + 4096, stream);
    if (big) convert_weights<<<1024, 256, 0, stream>>>(W, U, Wd);

    for (int t = 0; t < Tn; t++) {
        double* hin  = (t & 1) ? h1 : h0;
        double* hout = (t & 1) ? h0 : h1;
        u64* sprev = (t & 1) ? slots0 : slots1;   // written by C(t-1)
        u64* scur  = (t & 1) ? slots1 : slots0;   // zeroed by A(t), written by C(t)
        if (big) {
            lstm_step_mfma<<<dim3(512), 256, 0, stream>>>(x, Wd, W, bias, hin, hout, c,
                                                          sprev, scur, out, t);
        } else {
            lstm_step<<<dim3(512), 256, 0, stream>>>(x, W, U, bias, hin, hout, c,
                                                     sprev, scur, out, t);
        }
        logits_argmax<<<dim3(8, 64), 256, 0, stream>>>(hout, Wout, bout, scur);
    }
    // t = T-1 = 255 (odd) -> its slots live in slots1
    final_decode<<<1, Bn, 0, stream>>>(slots1, out);
}